// Round 6
// baseline (113.235 us; speedup 1.0000x reference)
//
#include <hip/hip_runtime.h>

// OriEmbeddingBlock: TensorProduct(1o x 1o -> 128x0e + 128x1e + 128x2e), uvw, shared weights.
//  - l=1 output block (cols 128..511) is identically ZERO (antisymmetric CG vs v(x)v).
//  - e3nn l=1 basis order within an ori row: 0=y, 1=z, 2=x.
//  - cols 0..127:   w0[col] * |v|^2 / sqrt(3)
//  - cols 512..1151: j=col-512, w2[j/5] * s2[j%5],
//    s2 = [sqrt(2)xy, sqrt(2)yz, sqrt(1/6)(2z^2-x^2-y^2), sqrt(2)zx, sqrt(1/2)(x^2-y^2)]
// Pure write-stream: 460.8 MB fp32 out.
// v6: LDS-staged DENSE regional streaming. v4/v5 both plateaued at 4.9 TB/s with
//     totally different wave structures -> limiter is the write pattern: ~4k
//     unsynchronized waves each emitting 1KB bursts at 2304B stride (gaps filled
//     by other waves at other times) = HBM page thrash. Fill (6.9 TB/s) writes
//     dense block-local regions. Here each block owns a CONTIGUOUS 921.6KB region;
//     tiles of 8 rows are built in LDS (fixed per-thread column chunk, coef/sel
//     hoisted), then streamed out as dense, block-synchronized sequential 36.9KB
//     bursts. 512 monotone regional streams chip-wide, fill-style.

#define THREADS 576              // 9 waves; 576 = 2 rows x 288 chunks
#define GRID 512                 // 2 blocks/CU; block owns 25 tiles = 200 rows
#define TPB 25                   // tiles per block
#define TROWS 8                  // rows per tile
#define CPRow 288                // float4 chunks per row
#define TCHUNKS (TROWS * CPRow)  // 2304 chunks per tile

__global__ __launch_bounds__(THREADS) void ori_embed_kernel(
    const float* __restrict__ ori,
    const float* __restrict__ weights,
    float* __restrict__ out,
    int n_rows)
{
    __shared__ float4 lds[2][TCHUNKS];       // 73728 B, double-buffered tile

    const int t = threadIdx.x;
    const int c = t % CPRow;                  // fixed column chunk (cols 4c..4c+3)
    const int ro = t / CPRow;                 // row offset within a pass (0 or 1)

    // Hoisted per-thread column descriptors.
    float coef[4];
    int sel[4];                               // 0 -> s0, 1..5 -> l=2 components
#pragma unroll
    for (int i = 0; i < 4; ++i) {
        const int col = 4 * c + i;
        if (col < 128)      { coef[i] = weights[col];  sel[i] = 0; }
        else if (col < 512) { coef[i] = 0.0f;          sel[i] = 0; }
        else { const int j = col - 512;
               coef[i] = weights[256 + j / 5];         sel[i] = 1 + j % 5; }
    }

    float4* __restrict__ out4 = reinterpret_cast<float4*>(out);
    const int NT = n_rows / TROWS;            // full tiles (12500 for N=100000)
    const int ti0 = blockIdx.x * TPB;
    const int ti1 = min(ti0 + TPB, NT);

    // Build one 8-row tile into LDS buffer kk. Thread handles rows r0+2p (p=0..3)
    // of the tile at its fixed chunk c.
    auto compute = [&](int ti, int kk) {
        const int rbase = ti * TROWS + ro;
#pragma unroll
        for (int p = 0; p < 4; ++p) {
            const int n = rbase + 2 * p;
            const float vy = ori[3 * n + 0];  // e3nn 0 = y
            const float vz = ori[3 * n + 1];  // 1 = z
            const float vx = ori[3 * n + 2];  // 2 = x
            const float xx = vx * vx, yy = vy * vy, zz = vz * vz;
            const float s0 = (xx + yy + zz) * 0.57735026918962576f;
            const float s1 = 1.41421356237309505f * (vx * vy);
            const float s2 = 1.41421356237309505f * (vy * vz);
            const float s3 = 0.40824829046386302f * (2.0f * zz - xx - yy);
            const float s4 = 1.41421356237309505f * (vz * vx);
            const float s5 = 0.70710678118654752f * (xx - yy);
            float r[4];
#pragma unroll
            for (int i = 0; i < 4; ++i) {
                float v = s0;
                v = (sel[i] == 1) ? s1 : v;
                v = (sel[i] == 2) ? s2 : v;
                v = (sel[i] == 3) ? s3 : v;
                v = (sel[i] == 4) ? s4 : v;
                v = (sel[i] == 5) ? s5 : v;
                r[i] = coef[i] * v;
            }
            lds[kk][(ro + 2 * p) * CPRow + c] = make_float4(r[0], r[1], r[2], r[3]);
        }
    };

    if (ti0 < ti1) {
        compute(ti0, 0);
        __syncthreads();
        int k = 0;
        for (int ti = ti0; ti < ti1; ++ti, k ^= 1) {
            if (ti + 1 < ti1) compute(ti + 1, k ^ 1);   // overlaps with stream below
            // Dense stream: tile = 36864 contiguous bytes, threads cover it in
            // 4 passes of 9 lane-contiguous KB (9.2KB per pass across the block).
            const size_t gb = (size_t)ti * TCHUNKS;
#pragma unroll
            for (int p = 0; p < 4; ++p) {
                const int idx = p * THREADS + t;
                out4[gb + idx] = lds[k][idx];
            }
            __syncthreads();
        }
    }

    // Tail rows (n_rows % 8 != 0) — empty for N=100000; last block handles them.
    if (blockIdx.x == GRID - 1 && ro == 0) {
        for (int n = NT * TROWS; n < n_rows; ++n) {
            const float vy = ori[3 * n + 0];
            const float vz = ori[3 * n + 1];
            const float vx = ori[3 * n + 2];
            const float xx = vx * vx, yy = vy * vy, zz = vz * vz;
            const float s0 = (xx + yy + zz) * 0.57735026918962576f;
            const float s1 = 1.41421356237309505f * (vx * vy);
            const float s2 = 1.41421356237309505f * (vy * vz);
            const float s3 = 0.40824829046386302f * (2.0f * zz - xx - yy);
            const float s4 = 1.41421356237309505f * (vz * vx);
            const float s5 = 0.70710678118654752f * (xx - yy);
            float r[4];
#pragma unroll
            for (int i = 0; i < 4; ++i) {
                float v = s0;
                v = (sel[i] == 1) ? s1 : v;
                v = (sel[i] == 2) ? s2 : v;
                v = (sel[i] == 3) ? s3 : v;
                v = (sel[i] == 4) ? s4 : v;
                v = (sel[i] == 5) ? s5 : v;
                r[i] = coef[i] * v;
            }
            out4[(size_t)n * CPRow + c] = make_float4(r[0], r[1], r[2], r[3]);
        }
    }
}

extern "C" void kernel_launch(void* const* d_in, const int* in_sizes, int n_in,
                              void* d_out, int out_size, void* d_ws, size_t ws_size,
                              hipStream_t stream) {
    const float* ori = (const float*)d_in[0];
    const float* weights = (const float*)d_in[1];
    float* out = (float*)d_out;
    const int n_rows = in_sizes[0] / 3;

    hipLaunchKernelGGL(ori_embed_kernel, dim3(GRID), dim3(THREADS), 0, stream,
                       ori, weights, out, n_rows);
}

// Round 8
// 96.151 us; speedup vs baseline: 1.1777x; 1.1777x over previous
//
#include <hip/hip_runtime.h>

// OriEmbeddingBlock: TensorProduct(1o x 1o -> 128x0e + 128x1e + 128x2e), uvw, shared weights.
//  - l=1 output block (cols 128..511) is identically ZERO (antisymmetric CG vs v(x)v).
//  - e3nn l=1 basis order within an ori row: 0=y, 1=z, 2=x.
//  - cols 0..127:   w0[col] * |v|^2 / sqrt(3)
//  - cols 512..1151: j=col-512, w2[j/5] * s2[j%5],
//    s2 = [sqrt(2)xy, sqrt(2)yz, sqrt(1/6)(2z^2-x^2-y^2), sqrt(2)zx, sqrt(1/2)(x^2-y^2)]
// Pure write-stream: 460.8 MB fp32 out.
// v7b = v5 (persistent single-generation, double-buffered 8-row batches, coalesced
//      1KB wave bursts) + NONTEMPORAL stores (via native ext_vector float4 — the
//      builtin rejects HIP_vector_type). Hypothesis: normal stores allocate dirty
//      L2 lines over a multi-MB live window (> 4MiB/XCD); HBM-side stream becomes
//      eviction-ordered and competes with allocates. nt streams write-once lines
//      past L2. Single-variable toggle vs v5.

#define THREADS 256
#define CPR 144                 // threads per row; row = 288 float4 chunks
#define GRID 1017               // %9==0 -> GRID*256/144 = 1808 groups; one generation
#define BATCH 8                 // rows per batch (6 float4 of ori, broadcast)
#define NB 7                    // batches per group -> 56 rows/group; 1808*56 >= 100000
#define RPG (BATCH * NB)

typedef float v4f __attribute__((ext_vector_type(4)));

__device__ __forceinline__ void emit_row(v4f* __restrict__ out4, int n, int c,
                                         float vy, float vz, float vx,
                                         const float coef[8], const int sel[8]) {
    const float xx = vx * vx, yy = vy * vy, zz = vz * vz;
    const float s0 = (xx + yy + zz) * 0.57735026918962576f;
    const float s1 = 1.41421356237309505f * (vx * vy);
    const float s2 = 1.41421356237309505f * (vy * vz);
    const float s3 = 0.40824829046386302f * (2.0f * zz - xx - yy);
    const float s4 = 1.41421356237309505f * (vz * vx);
    const float s5 = 0.70710678118654752f * (xx - yy);
    float r[8];
#pragma unroll
    for (int i = 0; i < 8; ++i) {
        float t = s0;
        t = (sel[i] == 1) ? s1 : t;
        t = (sel[i] == 2) ? s2 : t;
        t = (sel[i] == 3) ? s3 : t;
        t = (sel[i] == 4) ? s4 : t;
        t = (sel[i] == 5) ? s5 : t;
        r[i] = coef[i] * t;
    }
    const size_t ob = (size_t)n * (2 * CPR) + c;
    v4f a; a.x = r[0]; a.y = r[1]; a.z = r[2]; a.w = r[3];
    v4f b; b.x = r[4]; b.y = r[5]; b.z = r[6]; b.w = r[7];
    __builtin_nontemporal_store(a, &out4[ob]);
    __builtin_nontemporal_store(b, &out4[ob + CPR]);
}

__global__ __launch_bounds__(THREADS, 4) void ori_embed_kernel(
    const float* __restrict__ ori,
    const float* __restrict__ weights,
    float* __restrict__ out,
    int n_rows)
{
    const int tid = blockIdx.x * THREADS + threadIdx.x;
    const int c = tid % CPR;            // chunk within row (owns chunks c and c+144)
    const int g = tid / CPR;            // row group; 144 threads share the same rows
    const int r0 = g * RPG;
    if (r0 >= n_rows) return;

    // Columns owned: chunk A = cols 4c..4c+3, chunk B = cols 576+4c..576+4c+3.
    float coef[8];
    int sel[8];   // 0 -> s0 (l=0 value), 1..5 -> l=2 components
#pragma unroll
    for (int i = 0; i < 8; ++i) {
        const int col = (i < 4) ? (4 * c + i) : (576 + 4 * c + (i - 4));
        if (col < 128)      { coef[i] = weights[col];  sel[i] = 0; }
        else if (col < 512) { coef[i] = 0.0f;          sel[i] = 0; }
        else { const int j = col - 512;
               coef[i] = weights[256 + j / 5];         sel[i] = 1 + j % 5; }
    }

    v4f* __restrict__ out4 = reinterpret_cast<v4f*>(out);
    const v4f* __restrict__ src = reinterpret_cast<const v4f*>(ori);

    const int nb = min(NB, (n_rows - r0) / BATCH);  // full batches (N=100000 -> no remainder)
    const int base = 42 * g;                        // 3*r0/4 in float4 units (aligned)

    v4f cur[6], nxt[6];
    if (nb > 0) {
#pragma unroll
        for (int k = 0; k < 6; ++k) cur[k] = src[base + k];
    }
    for (int b = 0; b < nb; ++b) {
        const bool more = (b + 1 < nb);
        if (more) {
            // issue next batch's loads BEFORE this batch's 16 stores:
            // vmcnt retires oldest-first so the load wait never drains the store queue
#pragma unroll
            for (int k = 0; k < 6; ++k) nxt[k] = src[base + 6 * (b + 1) + k];
        }
        const float* f = reinterpret_cast<const float*>(cur);
        const int rb = r0 + b * BATCH;
#pragma unroll
        for (int j = 0; j < BATCH; ++j) {
            emit_row(out4, rb + j, c, f[3 * j + 0], f[3 * j + 1], f[3 * j + 2],
                     coef, sel);
        }
        if (more) {
#pragma unroll
            for (int k = 0; k < 6; ++k) cur[k] = nxt[k];
        }
    }

    // guarded scalar tail (never taken for N=100000: rows_left % 8 == 0 always)
    const int rend = min(r0 + RPG, n_rows);
    for (int n = r0 + nb * BATCH; n < rend; ++n) {
        emit_row(out4, n, c, ori[3 * n + 0], ori[3 * n + 1], ori[3 * n + 2],
                 coef, sel);
    }
}

extern "C" void kernel_launch(void* const* d_in, const int* in_sizes, int n_in,
                              void* d_out, int out_size, void* d_ws, size_t ws_size,
                              hipStream_t stream) {
    const float* ori = (const float*)d_in[0];
    const float* weights = (const float*)d_in[1];
    float* out = (float*)d_out;
    const int n_rows = in_sizes[0] / 3;

    hipLaunchKernelGGL(ori_embed_kernel, dim3(GRID), dim3(THREADS), 0, stream,
                       ori, weights, out, n_rows);
}